// Round 5
// baseline (57.023 us; speedup 1.0000x reference)
//
#include <hip/hip_runtime.h>
#include <math.h>

#define NCITY 384
#define BATCH 4
#define DIM   128
#define HID   256
#define M_TOT (BATCH * NCITY)   // 1536 rows (cities across batches)

// ---- workspace copy of ALL inputs (float offsets) --------------------------
// Written once per replay by import_kernel (one float4 per thread, maximal
// MLP). No other kernel touches d_in.
#define WC_WA1  0        // 32768
#define WC_BA1  32768    // 256
#define WC_WA2  33024    // 256
#define WC_WD1  33280    // 65536 (both halves)
#define WC_BD1  98816    // 256
#define WC_WD2  99072    // 256
#define WC_WE1  99328    // 512
#define WC_BE1  99840    // 256
#define WC_WE2  100096   // 32768
#define WC_BE2  132864   // 128
#define WC_CIT  132992   // 3072
#define WC_BD2  136064   // 1
#define WC_F4_TOTAL 34016

// ---------------------------------------------------------------------------
// K0: import everything d_in -> ws. 34016 float4 moves, one per thread,
// all issued concurrently (133 blocks x 256 threads) -> time ~ latency + Xfer.
// ---------------------------------------------------------------------------
__global__ __launch_bounds__(256) void import_kernel(
    const float* __restrict__ cities,
    const float* __restrict__ We1, const float* __restrict__ be1,
    const float* __restrict__ We2, const float* __restrict__ be2,
    const float* __restrict__ Wa1, const float* __restrict__ ba1,
    const float* __restrict__ wa2,
    const float* __restrict__ Wd1, const float* __restrict__ bd1,
    const float* __restrict__ wd2, const float* __restrict__ bd2,
    float* __restrict__ Wc)
{
    const int g = blockIdx.x * 256 + threadIdx.x;
    if (g < WC_F4_TOTAL) {
        const float4* src;
        if      (g < 8192)  src = (const float4*)Wa1 + g;
        else if (g < 8256)  src = (const float4*)ba1 + (g - 8192);
        else if (g < 8320)  src = (const float4*)wa2 + (g - 8256);
        else if (g < 24704) src = (const float4*)Wd1 + (g - 8320);
        else if (g < 24768) src = (const float4*)bd1 + (g - 24704);
        else if (g < 24832) src = (const float4*)wd2 + (g - 24768);
        else if (g < 24960) src = (const float4*)We1 + (g - 24832);
        else if (g < 25024) src = (const float4*)be1 + (g - 24960);
        else if (g < 33216) src = (const float4*)We2 + (g - 25024);
        else if (g < 33248) src = (const float4*)be2 + (g - 33216);
        else                src = (const float4*)cities + (g - 33248);
        ((float4*)Wc)[g] = *src;
    }
    if (g == 0) Wc[WC_BD2] = bd2[0];
}

// ---------------------------------------------------------------------------
// K1: emb = relu(cities@We1 + be1) @ We2 + be2        [1536 x 128]
// Tile 16 cities x 64 dims; grid (2, 96). Reads ONLY the ws copy.
// ---------------------------------------------------------------------------
__global__ __launch_bounds__(256) void emb_kernel(
    const float* __restrict__ Wc, float* __restrict__ emb)
{
    __shared__ float As[16 * 260];   // h1 tile, pad 256+4
    __shared__ float Bs[64 * 68];    // We2 chunk, pad 64+4
    __shared__ float cs[32];

    const int tid = threadIdx.x;
    const int c0  = blockIdx.y * 16;
    const int d0  = blockIdx.x * 64;

    if (tid < 32) cs[tid] = Wc[WC_CIT + c0 * 2 + tid];
    const float w0 = Wc[WC_WE1 + tid], w1 = Wc[WC_WE1 + HID + tid];
    const float b1 = Wc[WC_BE1 + tid];
    __syncthreads();

    // h1[c][k=tid]
    #pragma unroll
    for (int c = 0; c < 16; ++c) {
        const float2 xy = *(const float2*)&cs[2 * c];
        As[c * 260 + tid] = fmaxf(fmaf(xy.x, w0, fmaf(xy.y, w1, b1)), 0.f);
    }

    const int tm = tid >> 4, tn = tid & 15;
    float4 acc = {0.f, 0.f, 0.f, 0.f};

    for (int cc = 0; cc < 4; ++cc) {
        __syncthreads();
        {   // stage We2[cc*64 .. +64)[d0 .. d0+64) from ws copy
            const int u = tid & 15, kk = tid >> 4;
            #pragma unroll
            for (int m = 0; m < 4; ++m) {
                const int k = kk + m * 16;
                *(float4*)&Bs[k * 68 + u * 4] =
                    *(const float4*)&Wc[WC_WE2 + (cc * 64 + k) * DIM + d0 + u * 4];
            }
        }
        __syncthreads();
        #pragma unroll 4
        for (int k4 = 0; k4 < 16; ++k4) {
            const float4 a4 = *(const float4*)&As[tm * 260 + cc * 64 + k4 * 4];
            #pragma unroll
            for (int m = 0; m < 4; ++m) {
                const float4 b4 = *(const float4*)&Bs[(k4 * 4 + m) * 68 + tn * 4];
                const float a = (m == 0) ? a4.x : (m == 1) ? a4.y : (m == 2) ? a4.z : a4.w;
                acc.x = fmaf(a, b4.x, acc.x);
                acc.y = fmaf(a, b4.y, acc.y);
                acc.z = fmaf(a, b4.z, acc.z);
                acc.w = fmaf(a, b4.w, acc.w);
            }
        }
    }

    const float4 be4 = *(const float4*)&Wc[WC_BE2 + d0 + tn * 4];
    acc.x += be4.x; acc.y += be4.y; acc.z += be4.z; acc.w += be4.w;
    *(float4*)&emb[(c0 + tm) * DIM + d0 + tn * 4] = acc;
}

// ---------------------------------------------------------------------------
// K2: [att_h | Ai | Aj] = emb @ [Wa1 | Wd1[:128] | Wd1[128:]]   M=1536 N=768 K=128
// Tile 64 x 64, 4x4 per thread; grid (12, 24). All reads from ws.
// ---------------------------------------------------------------------------
__global__ __launch_bounds__(256) void heads_kernel(
    const float* __restrict__ emb, const float* __restrict__ Wc,
    float* __restrict__ score_part, float* __restrict__ Ai, float* __restrict__ Aj)
{
    __shared__ float As[64 * 132];   // emb tile, pad 128+4
    __shared__ float Bs[64 * 68];    // weight chunk, pad 64+4

    const int tid = threadIdx.x;
    const int r0  = blockIdx.y * 64;
    const int bn  = blockIdx.x;
    const int seg = bn >> 2;                 // 0=att 1=Ai 2=Aj
    const int cb  = (bn & 3) * 64;
    const float* Bsrc = (seg == 0) ? (Wc + WC_WA1)
                      : (seg == 1) ? (Wc + WC_WD1)
                                   : (Wc + WC_WD1 + DIM * HID);

    {   // stage A: emb[r0..r0+64)[0..128)
        const int c = tid >> 2, u = tid & 3;
        #pragma unroll
        for (int v = 0; v < 8; ++v)
            *(float4*)&As[c * 132 + u * 32 + v * 4] =
                *(const float4*)&emb[(r0 + c) * DIM + u * 32 + v * 4];
    }

    const int tm = tid >> 4, tn = tid & 15;
    float acc[4][4] = {};

    for (int cc = 0; cc < 2; ++cc) {
        __syncthreads();                     // A-writes (cc=0) / prev reads done
        {   // stage B chunk [64k x 64col]
            const int u = tid & 15, kk = tid >> 4;
            #pragma unroll
            for (int m = 0; m < 4; ++m) {
                const int k = kk + m * 16;
                *(float4*)&Bs[k * 68 + u * 4] =
                    *(const float4*)&Bsrc[(cc * 64 + k) * HID + cb + u * 4];
            }
        }
        __syncthreads();
        #pragma unroll 2
        for (int k4 = 0; k4 < 16; ++k4) {
            float4 a4[4];
            #pragma unroll
            for (int i = 0; i < 4; ++i)
                a4[i] = *(const float4*)&As[(tm * 4 + i) * 132 + cc * 64 + k4 * 4];
            #pragma unroll
            for (int m = 0; m < 4; ++m) {
                const float4 b4 = *(const float4*)&Bs[(k4 * 4 + m) * 68 + tn * 4];
                #pragma unroll
                for (int i = 0; i < 4; ++i) {
                    const float a = (m == 0) ? a4[i].x : (m == 1) ? a4[i].y
                                  : (m == 2) ? a4[i].z : a4[i].w;
                    acc[i][0] = fmaf(a, b4.x, acc[i][0]);
                    acc[i][1] = fmaf(a, b4.y, acc[i][1]);
                    acc[i][2] = fmaf(a, b4.z, acc[i][2]);
                    acc[i][3] = fmaf(a, b4.w, acc[i][3]);
                }
            }
        }
    }

    if (seg == 0) {
        const float4 ba4 = *(const float4*)&Wc[WC_BA1 + cb + tn * 4];
        const float4 wa4 = *(const float4*)&Wc[WC_WA2 + cb + tn * 4];
        #pragma unroll
        for (int i = 0; i < 4; ++i) {
            float s = fmaxf(acc[i][0] + ba4.x, 0.f) * wa4.x
                    + fmaxf(acc[i][1] + ba4.y, 0.f) * wa4.y
                    + fmaxf(acc[i][2] + ba4.z, 0.f) * wa4.z
                    + fmaxf(acc[i][3] + ba4.w, 0.f) * wa4.w;
            s += __shfl_xor(s, 1);
            s += __shfl_xor(s, 2);
            s += __shfl_xor(s, 4);
            s += __shfl_xor(s, 8);
            if (tn == 0)
                score_part[(bn & 3) * M_TOT + r0 + tm * 4 + i] = s;
        }
    } else if (seg == 1) {
        const float4 bd4 = *(const float4*)&Wc[WC_BD1 + cb + tn * 4];
        #pragma unroll
        for (int i = 0; i < 4; ++i) {
            float4 o = { acc[i][0] + bd4.x, acc[i][1] + bd4.y,
                         acc[i][2] + bd4.z, acc[i][3] + bd4.w };
            *(float4*)&Ai[(r0 + tm * 4 + i) * HID + cb + tn * 4] = o;
        }
    } else {
        #pragma unroll
        for (int i = 0; i < 4; ++i) {
            float4 o = { acc[i][0], acc[i][1], acc[i][2], acc[i][3] };
            *(float4*)&Aj[(r0 + tm * 4 + i) * HID + cb + tn * 4] = o;
        }
    }
}

// ---------------------------------------------------------------------------
// K3: softmax over N=384 per batch; input = 4 score partials summed.
// (ba2 dropped: softmax is shift-invariant.)
// ---------------------------------------------------------------------------
__global__ __launch_bounds__(NCITY) void softmax_kernel(
    const float* __restrict__ score_part, float* __restrict__ att)
{
    __shared__ float red[8];
    const int b = blockIdx.x, t = threadIdx.x;
    const int idx = b * NCITY + t;
    const float v = score_part[idx] + score_part[M_TOT + idx]
                  + score_part[2 * M_TOT + idx] + score_part[3 * M_TOT + idx];

    float m = v;
    #pragma unroll
    for (int off = 32; off > 0; off >>= 1)
        m = fmaxf(m, __shfl_down(m, off));
    if ((t & 63) == 0) red[t >> 6] = m;
    __syncthreads();
    m = red[0];
    #pragma unroll
    for (int w = 1; w < NCITY / 64; ++w) m = fmaxf(m, red[w]);

    const float e = __expf(v - m);
    float s = e;
    #pragma unroll
    for (int off = 32; off > 0; off >>= 1)
        s += __shfl_down(s, off);
    __syncthreads();
    if ((t & 63) == 0) red[t >> 6] = s;
    __syncthreads();
    s = 0.f;
    #pragma unroll
    for (int w = 0; w < NCITY / 64; ++w) s += red[w];

    att[idx] = e / s;
}

// ---------------------------------------------------------------------------
// K4: pairwise decoder. All non-ws inputs come from the ws weight copy.
// ---------------------------------------------------------------------------
__global__ __launch_bounds__(256) void pair_kernel(
    const float* __restrict__ Ai, const float* __restrict__ Aj,
    const float* __restrict__ Wc, float* __restrict__ p)
{
    __shared__ float ai_s[32 * HID];
    __shared__ float aj_s[32 * HID];

    const int tid = threadIdx.x;
    const int b  = blockIdx.z;
    const int i0 = blockIdx.y * 32;
    const int j0 = blockIdx.x * 32;

    const float* __restrict__ wd2 = Wc + WC_WD2;

    for (int t = tid; t < 32 * (HID / 4); t += 256) {
        const int r  = t >> 6;
        const int c4 = t & 63;
        const int cs = (c4 ^ (r & 7)) << 2;
        *(float4*)&ai_s[r * HID + cs] =
            *(const float4*)&Ai[(b * NCITY + i0 + r) * HID + (c4 << 2)];
        *(float4*)&aj_s[r * HID + cs] =
            *(const float4*)&Aj[(b * NCITY + j0 + r) * HID + (c4 << 2)];
    }
    __syncthreads();

    const int tx = tid & 15;
    const int ty = tid >> 4;
    const int sxi = ty & 7;
    const int sxj = tx & 7;

    float acc00 = 0.f, acc01 = 0.f, acc10 = 0.f, acc11 = 0.f;

    #pragma unroll 4
    for (int k4 = 0; k4 < HID / 4; ++k4) {
        const int k  = k4 << 2;
        const int ci = (k4 ^ sxi) << 2;
        const int cj = (k4 ^ sxj) << 2;
        const float4 w  = *(const float4*)&wd2[k];
        const float4 x0 = *(const float4*)&ai_s[ ty       * HID + ci];
        const float4 x1 = *(const float4*)&ai_s[(ty + 16) * HID + ci];
        const float4 y0 = *(const float4*)&aj_s[ tx       * HID + cj];
        const float4 y1 = *(const float4*)&aj_s[(tx + 16) * HID + cj];

#define PK(ACC, X, Y)                                                  \
        ACC = fmaf(fmaxf(X.x + Y.x, 0.f), w.x, ACC);                   \
        ACC = fmaf(fmaxf(X.y + Y.y, 0.f), w.y, ACC);                   \
        ACC = fmaf(fmaxf(X.z + Y.z, 0.f), w.z, ACC);                   \
        ACC = fmaf(fmaxf(X.w + Y.w, 0.f), w.w, ACC);
        PK(acc00, x0, y0)
        PK(acc01, x0, y1)
        PK(acc10, x1, y0)
        PK(acc11, x1, y1)
#undef PK
    }

    const float bd = Wc[WC_BD2];
    float accs[2][2] = {{acc00, acc01}, {acc10, acc11}};
    #pragma unroll
    for (int ii = 0; ii < 2; ++ii) {
        #pragma unroll
        for (int jj = 0; jj < 2; ++jj) {
            const int gi = i0 + ty + ii * 16;
            const int gj = j0 + tx + jj * 16;
            const float v = 1.f / (1.f + __expf(-(accs[ii][jj] + bd)));
            p[(b * NCITY + gi) * NCITY + gj] = (gi == gj) ? 0.f : v;
        }
    }
}

// ---------------------------------------------------------------------------
extern "C" void kernel_launch(void* const* d_in, const int* in_sizes, int n_in,
                              void* d_out, int out_size, void* d_ws, size_t ws_size,
                              hipStream_t stream)
{
    const float* cities = (const float*)d_in[0];
    const float* We1    = (const float*)d_in[1];
    const float* be1    = (const float*)d_in[2];
    const float* We2    = (const float*)d_in[3];
    const float* be2    = (const float*)d_in[4];
    const float* Wa1    = (const float*)d_in[5];
    const float* ba1    = (const float*)d_in[6];
    const float* wa2    = (const float*)d_in[7];
    const float* ba2    = (const float*)d_in[8];
    const float* Wd1    = (const float*)d_in[9];
    const float* bd1    = (const float*)d_in[10];
    const float* wd2    = (const float*)d_in[11];
    const float* bd2    = (const float*)d_in[12];
    (void)ba2;

    float* out_att = (float*)d_out;                 // [4,384]
    float* out_p   = out_att + BATCH * NCITY;       // [4,384,384]

    float* score_part = (float*)d_ws;               // [4][1536]
    float* emb        = score_part + 4 * M_TOT;     // [1536][128]
    float* Ai         = emb + M_TOT * DIM;          // [1536][256]
    float* Aj         = Ai + M_TOT * HID;           // [1536][256]
    float* Wc         = Aj + M_TOT * HID;           // full input copy (~0.55 MB)

    import_kernel<<<(WC_F4_TOTAL + 255) / 256, 256, 0, stream>>>(
        cities, We1, be1, We2, be2, Wa1, ba1, wa2, Wd1, bd1, wd2, bd2, Wc);

    emb_kernel<<<dim3(2, 96), 256, 0, stream>>>(Wc, emb);

    heads_kernel<<<dim3(12, 24), 256, 0, stream>>>(
        emb, Wc, score_part, Ai, Aj);

    softmax_kernel<<<BATCH, NCITY, 0, stream>>>(score_part, out_att);

    pair_kernel<<<dim3(NCITY / 32, NCITY / 32, BATCH), 256, 0, stream>>>(
        Ai, Aj, Wc, out_p);
}

// Round 7
// 37.578 us; speedup vs baseline: 1.5175x; 1.5175x over previous
//
#include <hip/hip_runtime.h>
#include <hip/hip_fp16.h>
#include <math.h>

#define NCITY 384
#define BATCH 4
#define DIM   128
#define HID   256
#define M_TOT (BATCH * NCITY)   // 1536
#define TR    6                 // rows per encoder block -> 256 blocks

#define CHUNK_FLOATS 32768      // 128 KB weight chunk

// ---------------------------------------------------------------------------
// Packed f16 ops via raw VOP3P asm (ROCm header's __hmax2 is broken on gfx950).
// Operands are 32-bit regs holding 2x f16.
// ---------------------------------------------------------------------------
__device__ __forceinline__ unsigned pk_add(unsigned a, unsigned b) {
    unsigned r;
    asm("v_pk_add_f16 %0, %1, %2" : "=v"(r) : "v"(a), "v"(b));
    return r;
}
__device__ __forceinline__ unsigned pk_max0(unsigned a) {
    unsigned r;
    asm("v_pk_max_f16 %0, %1, %2" : "=v"(r) : "v"(a), "v"(0u));
    return r;
}
__device__ __forceinline__ unsigned pk_fma(unsigned a, unsigned b, unsigned c) {
    unsigned r;
    asm("v_pk_fma_f16 %0, %1, %2, %3" : "=v"(r) : "v"(a), "v"(b), "v"(c));
    return r;
}
__device__ __forceinline__ unsigned pack2(float a, float b) {
    union { __half2 h2; unsigned u; } c;
    c.h2 = __float22half2_rn(make_float2(a, b));
    return c.u;
}
__device__ __forceinline__ float sum2(unsigned u) {
    union { unsigned u; __half2 h2; } c;
    c.u = u;
    return __low2float(c.h2) + __high2float(c.h2);
}

// ---------------------------------------------------------------------------
// Bulk global->LDS stage of one 128KB chunk via global_load_lds width=16.
// ---------------------------------------------------------------------------
__device__ __forceinline__ void stage128(const float* __restrict__ gsrc,
                                         float* lbuf, int tid)
{
    const int lane = tid & 63;
    const int wv   = tid >> 6;
    #pragma unroll
    for (int i = 0; i < 32; ++i) {
        const int slot = i * 4 + wv;              // 0..127, 1KB each
        __builtin_amdgcn_global_load_lds(
            (const __attribute__((address_space(1))) void*)(gsrc + slot * 256 + lane * 4),
            (__attribute__((address_space(3))) void*)(lbuf + slot * 256),
            16, 0, 0);
    }
}

// ---------------------------------------------------------------------------
// GEMM of one staged chunk W[128][256] against emb_s[TR][128] (R2-proven).
// ---------------------------------------------------------------------------
__device__ __forceinline__ void chunk_gemm(float* wbuf,
                                           const float (*emb_s)[DIM],
                                           int tid, float out6[TR])
{
    const int c4 = tid & 63;
    const int wv = tid >> 6;
    const int k0 = wv * 32;

    float4 acc[TR];
    #pragma unroll
    for (int rr = 0; rr < TR; ++rr) { acc[rr].x = 0.f; acc[rr].y = 0.f; acc[rr].z = 0.f; acc[rr].w = 0.f; }

    #pragma unroll 2
    for (int kb = 0; kb < 32; kb += 4) {
        float4 ev[TR];
        #pragma unroll
        for (int rr = 0; rr < TR; ++rr)
            ev[rr] = *(const float4*)&emb_s[rr][k0 + kb];
        #pragma unroll
        for (int kk = 0; kk < 4; ++kk) {
            const float4 w4 = *(const float4*)&wbuf[(k0 + kb + kk) * HID + c4 * 4];
            #pragma unroll
            for (int rr = 0; rr < TR; ++rr) {
                const float e = ((const float*)&ev[rr])[kk];
                acc[rr].x = fmaf(e, w4.x, acc[rr].x);
                acc[rr].y = fmaf(e, w4.y, acc[rr].y);
                acc[rr].z = fmaf(e, w4.z, acc[rr].z);
                acc[rr].w = fmaf(e, w4.w, acc[rr].w);
            }
        }
    }
    __syncthreads();                       // all W reads done before overwrite
    #pragma unroll
    for (int rr = 0; rr < TR; ++rr)
        *(float4*)&wbuf[(wv * TR + rr) * HID + c4 * 4] = acc[rr];
    __syncthreads();
    #pragma unroll
    for (int rr = 0; rr < TR; ++rr)
        out6[rr] = wbuf[(0 * TR + rr) * HID + tid] + wbuf[(1 * TR + rr) * HID + tid]
                 + wbuf[(2 * TR + rr) * HID + tid] + wbuf[(3 * TR + rr) * HID + tid];
}

// ---------------------------------------------------------------------------
// K1: fused encoder (verbatim R2 — best measured structure).
// ---------------------------------------------------------------------------
__global__ __launch_bounds__(256) void encoder_kernel(
    const float* __restrict__ cities,
    const float* __restrict__ We1, const float* __restrict__ be1,
    const float* __restrict__ We2, const float* __restrict__ be2,
    const float* __restrict__ Wa1, const float* __restrict__ ba1,
    const float* __restrict__ wa2, const float* __restrict__ ba2,
    const float* __restrict__ Wd1, const float* __restrict__ bd1,
    float* __restrict__ score, float* __restrict__ Ai, float* __restrict__ Aj)
{
    __shared__ float wbuf[CHUNK_FLOATS];     // 128 KB
    __shared__ float h1_s[TR][HID];
    __shared__ float emb_s[TR][DIM];
    __shared__ float red2[4][TR];

    const int tid = threadIdx.x;
    const int r0  = blockIdx.x * TR;

    stage128(We2, wbuf, tid);

    {
        const float w0 = We1[tid], w1 = We1[HID + tid], b = be1[tid];
        #pragma unroll
        for (int rr = 0; rr < TR; ++rr) {
            const float cx = cities[(r0 + rr) * 2];
            const float cy = cities[(r0 + rr) * 2 + 1];
            h1_s[rr][tid] = fmaxf(fmaf(cx, w0, fmaf(cy, w1, b)), 0.f);
        }
    }
    __syncthreads();    // drains We2 DMA + h1 visible

    // ---- emb = h1 @ We2 + be2 ----------------------------------------------
    {
        const int d4 = tid & 31;
        const int ks = tid >> 5;
        const int k0 = ks * 32;
        float4 acc[TR];
        #pragma unroll
        for (int rr = 0; rr < TR; ++rr) { acc[rr].x = 0.f; acc[rr].y = 0.f; acc[rr].z = 0.f; acc[rr].w = 0.f; }

        #pragma unroll 2
        for (int kb = 0; kb < 32; kb += 4) {
            float4 hv[TR];
            #pragma unroll
            for (int rr = 0; rr < TR; ++rr)
                hv[rr] = *(const float4*)&h1_s[rr][k0 + kb];
            #pragma unroll
            for (int kk = 0; kk < 4; ++kk) {
                const float4 w4 = *(const float4*)&wbuf[(k0 + kb + kk) * DIM + d4 * 4];
                #pragma unroll
                for (int rr = 0; rr < TR; ++rr) {
                    const float h = ((const float*)&hv[rr])[kk];
                    acc[rr].x = fmaf(h, w4.x, acc[rr].x);
                    acc[rr].y = fmaf(h, w4.y, acc[rr].y);
                    acc[rr].z = fmaf(h, w4.z, acc[rr].z);
                    acc[rr].w = fmaf(h, w4.w, acc[rr].w);
                }
            }
        }
        #pragma unroll
        for (int rr = 0; rr < TR; ++rr) {
            acc[rr].x += __shfl_xor(acc[rr].x, 32);
            acc[rr].y += __shfl_xor(acc[rr].y, 32);
            acc[rr].z += __shfl_xor(acc[rr].z, 32);
            acc[rr].w += __shfl_xor(acc[rr].w, 32);
        }
        __syncthreads();
        if ((tid & 63) < 32) {
            const int wv = tid >> 6;
            #pragma unroll
            for (int rr = 0; rr < TR; ++rr)
                *(float4*)&wbuf[(wv * TR + rr) * DIM + d4 * 4] = acc[rr];
        }
        __syncthreads();
        for (int o = tid; o < TR * DIM; o += 256) {
            const int rr = o >> 7, d = o & (DIM - 1);
            emb_s[rr][d] = wbuf[(0 * TR + rr) * DIM + d] + wbuf[(1 * TR + rr) * DIM + d]
                         + wbuf[(2 * TR + rr) * DIM + d] + wbuf[(3 * TR + rr) * DIM + d]
                         + be2[d];
        }
        __syncthreads();
    }

    // ---- chunk 1: Wa1 -> attention scores ----------------------------------
    stage128(Wa1, wbuf, tid);
    __syncthreads();
    {
        float o6[TR];
        chunk_gemm(wbuf, emb_s, tid, o6);
        const float ba1v = ba1[tid], wa2v = wa2[tid];
        const int wv = tid >> 6;
        #pragma unroll
        for (int rr = 0; rr < TR; ++rr) {
            float v = fmaxf(o6[rr] + ba1v, 0.f) * wa2v;
            #pragma unroll
            for (int off = 32; off > 0; off >>= 1)
                v += __shfl_down(v, off);
            if ((tid & 63) == 0) red2[wv][rr] = v;
        }
        __syncthreads();
        if (tid < TR)
            score[r0 + tid] = red2[0][tid] + red2[1][tid] + red2[2][tid] + red2[3][tid];
        // ba2 dropped: softmax is shift-invariant
    }

    // ---- chunk 2: Wd1 rows 0..127 -> Ai ------------------------------------
    stage128(Wd1, wbuf, tid);
    __syncthreads();
    {
        float o6[TR];
        chunk_gemm(wbuf, emb_s, tid, o6);
        const float bd1v = bd1[tid];
        #pragma unroll
        for (int rr = 0; rr < TR; ++rr)
            Ai[(r0 + rr) * HID + tid] = o6[rr] + bd1v;
        __syncthreads();
    }

    // ---- chunk 3: Wd1 rows 128..255 -> Aj ----------------------------------
    stage128(Wd1 + DIM * HID, wbuf, tid);
    __syncthreads();
    {
        float o6[TR];
        chunk_gemm(wbuf, emb_s, tid, o6);
        #pragma unroll
        for (int rr = 0; rr < TR; ++rr)
            Aj[(r0 + rr) * HID + tid] = o6[rr];
    }
}

// ---------------------------------------------------------------------------
// K2: pairwise decoder in packed f16 (raw VOP3P) + fused softmax.
// grid (145, 4): bx<144 -> 32x32 (i,j) tile; bx==144 -> softmax for batch by.
// LDS tiles as f16, 16B-unit XOR swizzle: ai reads broadcast (conflict-free),
// aj reads 2-way alias (free per m136).
// ---------------------------------------------------------------------------
union H8 { float4 f4; unsigned u[4]; };

__global__ __launch_bounds__(256) void pair_sm_kernel(
    const float* __restrict__ Ai, const float* __restrict__ Aj,
    const float* __restrict__ wd2, const float* __restrict__ bd2,
    const float* __restrict__ score, float* __restrict__ att,
    float* __restrict__ p)
{
    const int tid = threadIdx.x;
    const int b   = blockIdx.y;

    if (blockIdx.x == 144) {     // ---- softmax block for batch b ------------
        __shared__ float red[8];
        const int t = tid;
        const float v0 = score[b * NCITY + t];
        const bool  h2v = (t < NCITY - 256);
        const float v1 = h2v ? score[b * NCITY + 256 + t] : -3.4e38f;
        float m = fmaxf(v0, v1);
        #pragma unroll
        for (int off = 32; off > 0; off >>= 1)
            m = fmaxf(m, __shfl_down(m, off));
        if ((t & 63) == 0) red[t >> 6] = m;
        __syncthreads();
        m = fmaxf(fmaxf(red[0], red[1]), fmaxf(red[2], red[3]));
        const float e0 = __expf(v0 - m);
        const float e1 = h2v ? __expf(v1 - m) : 0.f;
        float s = e0 + e1;
        #pragma unroll
        for (int off = 32; off > 0; off >>= 1)
            s += __shfl_down(s, off);
        if ((t & 63) == 0) red[4 + (t >> 6)] = s;
        __syncthreads();
        s = red[4] + red[5] + red[6] + red[7];
        att[b * NCITY + t] = e0 / s;
        if (h2v) att[b * NCITY + 256 + t] = e1 / s;
        return;
    }

    // ---- pair tile ---------------------------------------------------------
    __shared__ __half ai_s[32 * HID];    // 16 KB
    __shared__ __half aj_s[32 * HID];    // 16 KB
    __shared__ unsigned wd2h[HID / 2];   // 512 B

    const int i0 = (blockIdx.x / 12) * 32;
    const int j0 = (blockIdx.x % 12) * 32;

    if (tid < HID / 2) {
        const float2 w2 = *(const float2*)&wd2[tid * 2];
        wd2h[tid] = pack2(w2.x, w2.y);
    }

    // stage + f32->f16 convert: unit = 8 halfs (16B), 32 units/row
    for (int u = tid; u < 32 * 32; u += 256) {
        const int r = u >> 5, s = u & 31;
        const int su = (s ^ (r & 15)) * 8;
        {
            const int g = (b * NCITY + i0 + r) * HID + s * 8;
            const float4 f0 = *(const float4*)&Ai[g];
            const float4 f1 = *(const float4*)&Ai[g + 4];
            H8 pk;
            pk.u[0] = pack2(f0.x, f0.y);
            pk.u[1] = pack2(f0.z, f0.w);
            pk.u[2] = pack2(f1.x, f1.y);
            pk.u[3] = pack2(f1.z, f1.w);
            *(float4*)&ai_s[r * HID + su] = pk.f4;
        }
        {
            const int g = (b * NCITY + j0 + r) * HID + s * 8;
            const float4 f0 = *(const float4*)&Aj[g];
            const float4 f1 = *(const float4*)&Aj[g + 4];
            H8 pk;
            pk.u[0] = pack2(f0.x, f0.y);
            pk.u[1] = pack2(f0.z, f0.w);
            pk.u[2] = pack2(f1.x, f1.y);
            pk.u[3] = pack2(f1.z, f1.w);
            *(float4*)&aj_s[r * HID + su] = pk.f4;
        }
    }
    __syncthreads();

    const int tx = tid & 15;        // j within tile (and +16)
    const int ty = tid >> 4;        // i within tile (and +16)

    unsigned a00A = 0u, a00B = 0u, a01A = 0u, a01B = 0u;
    unsigned a10A = 0u, a10B = 0u, a11A = 0u, a11B = 0u;

    #pragma unroll 4
    for (int k8 = 0; k8 < 32; ++k8) {
        const int ci = (k8 ^ ty) * 8;
        const int cj = (k8 ^ tx) * 8;
        H8 x0, x1, y0, y1;
        x0.f4 = *(const float4*)&ai_s[ ty       * HID + ci];
        x1.f4 = *(const float4*)&ai_s[(ty + 16) * HID + ci];
        y0.f4 = *(const float4*)&aj_s[ tx       * HID + cj];
        y1.f4 = *(const float4*)&aj_s[(tx + 16) * HID + cj];

        #pragma unroll
        for (int q = 0; q < 4; ++q) {
            const unsigned w = wd2h[k8 * 4 + q];
            const unsigned t00 = pk_max0(pk_add(x0.u[q], y0.u[q]));
            const unsigned t01 = pk_max0(pk_add(x0.u[q], y1.u[q]));
            const unsigned t10 = pk_max0(pk_add(x1.u[q], y0.u[q]));
            const unsigned t11 = pk_max0(pk_add(x1.u[q], y1.u[q]));
            if (q < 2) {
                a00A = pk_fma(t00, w, a00A);
                a01A = pk_fma(t01, w, a01A);
                a10A = pk_fma(t10, w, a10A);
                a11A = pk_fma(t11, w, a11A);
            } else {
                a00B = pk_fma(t00, w, a00B);
                a01B = pk_fma(t01, w, a01B);
                a10B = pk_fma(t10, w, a10B);
                a11B = pk_fma(t11, w, a11B);
            }
        }
    }

    const float bd = bd2[0];
    float accs[2][2];
    accs[0][0] = sum2(a00A) + sum2(a00B);
    accs[0][1] = sum2(a01A) + sum2(a01B);
    accs[1][0] = sum2(a10A) + sum2(a10B);
    accs[1][1] = sum2(a11A) + sum2(a11B);

    #pragma unroll
    for (int ii = 0; ii < 2; ++ii) {
        #pragma unroll
        for (int jj = 0; jj < 2; ++jj) {
            const int gi = i0 + ty + ii * 16;
            const int gj = j0 + tx + jj * 16;
            const float v = 1.f / (1.f + __expf(-(accs[ii][jj] + bd)));
            p[(b * NCITY + gi) * NCITY + gj] = (gi == gj) ? 0.f : v;
        }
    }
}

// ---------------------------------------------------------------------------
extern "C" void kernel_launch(void* const* d_in, const int* in_sizes, int n_in,
                              void* d_out, int out_size, void* d_ws, size_t ws_size,
                              hipStream_t stream)
{
    const float* cities = (const float*)d_in[0];
    const float* We1    = (const float*)d_in[1];
    const float* be1    = (const float*)d_in[2];
    const float* We2    = (const float*)d_in[3];
    const float* be2    = (const float*)d_in[4];
    const float* Wa1    = (const float*)d_in[5];
    const float* ba1    = (const float*)d_in[6];
    const float* wa2    = (const float*)d_in[7];
    const float* ba2    = (const float*)d_in[8];
    const float* Wd1    = (const float*)d_in[9];
    const float* bd1    = (const float*)d_in[10];
    const float* wd2    = (const float*)d_in[11];
    const float* bd2    = (const float*)d_in[12];
    (void)ba2;

    float* out_att = (float*)d_out;                 // [4,384]
    float* out_p   = out_att + BATCH * NCITY;       // [4,384,384]

    float* score = (float*)d_ws;                    // 1536
    float* Ai    = score + M_TOT;                   // 1536*256
    float* Aj    = Ai + M_TOT * HID;                // 1536*256

    encoder_kernel<<<M_TOT / TR, 256, 0, stream>>>(
        cities, We1, be1, We2, be2, Wa1, ba1, wa2, ba2, Wd1, bd1,
        score, Ai, Aj);

    pair_sm_kernel<<<dim3(145, BATCH), 256, 0, stream>>>(
        Ai, Aj, wd2, bd2, score, out_att, out_p);
}